// Round 17
// baseline (140.203 us; speedup 1.0000x reference)
//
#include <hip/hip_runtime.h>
#include <math.h>

#define N 2048
#define F 128
#define O 128
#define E 16

typedef __attribute__((ext_vector_type(8))) short          shortx8;
typedef __attribute__((ext_vector_type(8))) unsigned short u16x8;
typedef __attribute__((ext_vector_type(4))) unsigned short u16x4;
typedef __attribute__((ext_vector_type(4))) float          floatx4;

static __device__ __forceinline__ unsigned short f2bf(float f) {
    unsigned int u = __float_as_uint(f);
    unsigned int r = (u + 0x7FFFu + ((u >> 16) & 1u)) >> 16;
    return (unsigned short)r;
}

// ---------------- Kernel 1: preT[b][o][n] = (x @ w_b)[n][o] via MFMA ----------------
__global__ __launch_bounds__(256)
void pre_t(const float* __restrict__ x,
           const float* __restrict__ w0,
           const float* __restrict__ w1,
           unsigned short* __restrict__ preT) {
    __shared__ unsigned short wT[128 * 136];   // w^T bf16, padded stride 136
    const int t  = threadIdx.x;
    const int n0 = blockIdx.x * 16;
    const int b  = blockIdx.y;
    const float* __restrict__ wsrc = b ? w1 : w0;

#pragma unroll
    for (int i = 0; i < 64; ++i) {
        const int idx = i * 256 + t;          // coalesced read of w[k][o]
        const int k = idx >> 7, o = idx & 127;
        wT[o * 136 + k] = f2bf(wsrc[idx]);
    }
    __syncthreads();

    const int lane = t & 63;
    const int wv   = t >> 6;        // 0..3: 32-col group
    const int row  = lane & 15;
    const int kg   = lane >> 4;
    const int col0 = wv * 32 + row;

    floatx4 acc0 = {0.f, 0.f, 0.f, 0.f};
    floatx4 acc1 = {0.f, 0.f, 0.f, 0.f};

#pragma unroll
    for (int kk = 0; kk < 4; ++kk) {
        const float* xp = x + (size_t)(n0 + row) * F + kk * 32 + kg * 8;
        const float4 f0 = *(const float4*)(xp);
        const float4 f1 = *(const float4*)(xp + 4);
        shortx8 a;
        a[0] = (short)f2bf(f0.x); a[1] = (short)f2bf(f0.y);
        a[2] = (short)f2bf(f0.z); a[3] = (short)f2bf(f0.w);
        a[4] = (short)f2bf(f1.x); a[5] = (short)f2bf(f1.y);
        a[6] = (short)f2bf(f1.z); a[7] = (short)f2bf(f1.w);
        const shortx8 bA = *(const shortx8*)(wT + col0 * 136 + kk * 32 + kg * 8);
        const shortx8 bB = *(const shortx8*)(wT + (col0 + 16) * 136 + kk * 32 + kg * 8);
        acc0 = __builtin_amdgcn_mfma_f32_16x16x32_bf16(a, bA, acc0, 0, 0, 0);
        acc1 = __builtin_amdgcn_mfma_f32_16x16x32_bf16(a, bB, acc1, 0, 0, 0);
    }

    const int prow = kg * 4;
    u16x4 s0, s1;
#pragma unroll
    for (int j = 0; j < 4; ++j) { s0[j] = f2bf(acc0[j]); s1[j] = f2bf(acc1[j]); }
    *(u16x4*)(preT + ((size_t)b * O + col0) * N + n0 + prow)      = s0;
    *(u16x4*)(preT + ((size_t)b * O + col0 + 16) * N + n0 + prow) = s1;
}

// ---------------- Kernel 2: gate (R10-form: 4 lanes/pair, 65536 blocks) -------------
__global__ __launch_bounds__(256)
void gate_kernel(const float* __restrict__ ef,
                 const float* __restrict__ we,
                 const float* __restrict__ be,
                 const float* __restrict__ sup1,
                 unsigned short* __restrict__ G) {
    const size_t tid  = (size_t)blockIdx.x * 256 + threadIdx.x;
    const size_t pair = tid >> 2;
    const int    sub  = (int)(threadIdx.x & 3);
    const float4 e4 = ((const float4*)ef)[pair * 4 + sub];
    const float4 w4 = ((const float4*)we)[pair * 4 + sub];
    float v = e4.x * w4.x + e4.y * w4.y + e4.z * w4.z + e4.w * w4.w;
    v += __shfl_xor(v, 1);
    v += __shfl_xor(v, 2);
    if (sub == 0) {
        const float t = v + be[pair];
        const float g = (1.f / (1.f + __expf(-t))) * sup1[pair];
        G[pair] = f2bf(g);
    }
}

// ---------------- Kernel 3: dual GEMM, 8-wave in-block split-K (R10 + unroll 4) -----
__global__ __launch_bounds__(512, 4)
void gemm_direct(const float* __restrict__ S0,
                 const unsigned short* __restrict__ G,
                 const unsigned short* __restrict__ preT,
                 const float* __restrict__ bias,
                 float* __restrict__ out) {
    __shared__ float red[8][16][36];

    const int bx   = blockIdx.x;
    const int orig = (bx & 7) * 64 + (bx >> 3);  // group 4 col-blocks per XCD
    const int rb   = orig >> 2;                  // 0..127
    const int cg   = orig & 3;                   // 0..3
    const int n0   = rb * 16;

    const int t    = threadIdx.x;
    const int lane = t & 63;
    const int wv   = t >> 6;                     // 0..7
    const int m_b  = wv * 256;
    const int row  = lane & 15;
    const int kg   = lane >> 4;
    const int col0 = cg * 32 + row;

    const float*          aS = S0   + (size_t)(n0 + row) * N + m_b + kg * 8;
    const unsigned short* aG = G    + (size_t)(n0 + row) * N + m_b + kg * 8;
    const unsigned short* b0 = preT + (size_t)col0 * N        + m_b + kg * 8;
    const unsigned short* b1 = b0 + (size_t)16 * N;
    const unsigned short* c0 = b0 + (size_t)O * N;   // preT[1]
    const unsigned short* c1 = b1 + (size_t)O * N;

    floatx4 acc0 = {0.f, 0.f, 0.f, 0.f};
    floatx4 acc1 = {0.f, 0.f, 0.f, 0.f};

#pragma unroll 4
    for (int s = 0; s < 8; ++s) {
        const int mo = s * 32;
        const float4 f0 = *(const float4*)(aS + mo);
        const float4 f1 = *(const float4*)(aS + mo + 4);
        const shortx8 a_g = *(const shortx8*)(aG + mo);
        const shortx8 b00 = *(const shortx8*)(b0 + mo);
        const shortx8 b01 = *(const shortx8*)(b1 + mo);
        const shortx8 b10 = *(const shortx8*)(c0 + mo);
        const shortx8 b11 = *(const shortx8*)(c1 + mo);
        shortx8 a_s;
        a_s[0] = (short)f2bf(f0.x); a_s[1] = (short)f2bf(f0.y);
        a_s[2] = (short)f2bf(f0.z); a_s[3] = (short)f2bf(f0.w);
        a_s[4] = (short)f2bf(f1.x); a_s[5] = (short)f2bf(f1.y);
        a_s[6] = (short)f2bf(f1.z); a_s[7] = (short)f2bf(f1.w);
        acc0 = __builtin_amdgcn_mfma_f32_16x16x32_bf16(a_s, b00, acc0, 0, 0, 0);
        acc0 = __builtin_amdgcn_mfma_f32_16x16x32_bf16(a_g, b10, acc0, 0, 0, 0);
        acc1 = __builtin_amdgcn_mfma_f32_16x16x32_bf16(a_s, b01, acc1, 0, 0, 0);
        acc1 = __builtin_amdgcn_mfma_f32_16x16x32_bf16(a_g, b11, acc1, 0, 0, 0);
    }

    // stash per-wave acc in LDS: C/D col = lane&15, row = kg*4 + j
    const int prow = kg * 4;
#pragma unroll
    for (int j = 0; j < 4; ++j) {
        red[wv][prow + j][row]      = acc0[j];
        red[wv][prow + j][16 + row] = acc1[j];
    }
    __syncthreads();

    // first 256 threads: one row r, two cols c,c+1; sum over 8 waves
    if (t < 256) {
        const int r = t >> 4;
        const int c = (t & 15) * 2;
        float v0 = 0.f, v1 = 0.f;
#pragma unroll
        for (int w = 0; w < 8; ++w) {
            v0 += red[w][r][c];
            v1 += red[w][r][c + 1];
        }
        v0 = fmaxf(v0 + bias[cg * 32 + c],     0.f);
        v1 = fmaxf(v1 + bias[cg * 32 + c + 1], 0.f);
        float2 o2; o2.x = v0; o2.y = v1;
        *(float2*)(out + (size_t)(n0 + r) * O + cg * 32 + c) = o2;
    }
}

extern "C" void kernel_launch(void* const* d_in, const int* in_sizes, int n_in,
                              void* d_out, int out_size, void* d_ws, size_t ws_size,
                              hipStream_t stream) {
    const float* x   = (const float*)d_in[0];   // [N,F]
    const float* sup = (const float*)d_in[1];   // [2,N,N]
    const float* ef  = (const float*)d_in[2];   // [N,N,E]
    const float* we  = (const float*)d_in[3];   // [N,N,E]
    const float* be  = (const float*)d_in[4];   // [N,N]
    const float* w0  = (const float*)d_in[5];   // [F,O]
    const float* w1  = (const float*)d_in[6];   // [F,O]
    const float* b   = (const float*)d_in[7];   // [O]
    float* out = (float*)d_out;

    unsigned short* preT = (unsigned short*)d_ws;    // [2][O][N] bf16, 1 MB
    unsigned short* G    = preT + 2 * (size_t)N * O; // [N][N]   bf16, 8.4 MB

    pre_t<<<dim3(N / 16, 2), 256, 0, stream>>>(x, w0, w1, preT);
    gate_kernel<<<(unsigned)((size_t)N * N * 4 / 256), 256, 0, stream>>>(
        ef, we, be, sup + (size_t)N * N, G);
    gemm_direct<<<512, 512, 0, stream>>>(sup, G, preT, b, out);
}

// Round 18
// 129.105 us; speedup vs baseline: 1.0860x; 1.0860x over previous
//
#include <hip/hip_runtime.h>
#include <math.h>

#define N 2048
#define F 128
#define O 128
#define E 16

typedef __attribute__((ext_vector_type(8))) short          shortx8;
typedef __attribute__((ext_vector_type(8))) unsigned short u16x8;
typedef __attribute__((ext_vector_type(4))) unsigned short u16x4;
typedef __attribute__((ext_vector_type(4))) float          floatx4;

static __device__ __forceinline__ unsigned short f2bf(float f) {
    unsigned int u = __float_as_uint(f);
    unsigned int r = (u + 0x7FFFu + ((u >> 16) & 1u)) >> 16;
    return (unsigned short)r;
}

// ---------------- Kernel 1: preT[b][o][n] = (x @ w_b)[n][o] via MFMA ----------------
__global__ __launch_bounds__(256)
void pre_t(const float* __restrict__ x,
           const float* __restrict__ w0,
           const float* __restrict__ w1,
           unsigned short* __restrict__ preT) {
    __shared__ unsigned short wT[128 * 136];   // w^T bf16, padded stride 136
    const int t  = threadIdx.x;
    const int n0 = blockIdx.x * 16;
    const int b  = blockIdx.y;
    const float* __restrict__ wsrc = b ? w1 : w0;

#pragma unroll
    for (int i = 0; i < 64; ++i) {
        const int idx = i * 256 + t;          // coalesced read of w[k][o]
        const int k = idx >> 7, o = idx & 127;
        wT[o * 136 + k] = f2bf(wsrc[idx]);
    }
    __syncthreads();

    const int lane = t & 63;
    const int wv   = t >> 6;        // 0..3: 32-col group
    const int row  = lane & 15;
    const int kg   = lane >> 4;
    const int col0 = wv * 32 + row;

    floatx4 acc0 = {0.f, 0.f, 0.f, 0.f};
    floatx4 acc1 = {0.f, 0.f, 0.f, 0.f};

#pragma unroll
    for (int kk = 0; kk < 4; ++kk) {
        const float* xp = x + (size_t)(n0 + row) * F + kk * 32 + kg * 8;
        const float4 f0 = *(const float4*)(xp);
        const float4 f1 = *(const float4*)(xp + 4);
        shortx8 a;
        a[0] = (short)f2bf(f0.x); a[1] = (short)f2bf(f0.y);
        a[2] = (short)f2bf(f0.z); a[3] = (short)f2bf(f0.w);
        a[4] = (short)f2bf(f1.x); a[5] = (short)f2bf(f1.y);
        a[6] = (short)f2bf(f1.z); a[7] = (short)f2bf(f1.w);
        const shortx8 bA = *(const shortx8*)(wT + col0 * 136 + kk * 32 + kg * 8);
        const shortx8 bB = *(const shortx8*)(wT + (col0 + 16) * 136 + kk * 32 + kg * 8);
        acc0 = __builtin_amdgcn_mfma_f32_16x16x32_bf16(a, bA, acc0, 0, 0, 0);
        acc1 = __builtin_amdgcn_mfma_f32_16x16x32_bf16(a, bB, acc1, 0, 0, 0);
    }

    const int prow = kg * 4;
    u16x4 s0, s1;
#pragma unroll
    for (int j = 0; j < 4; ++j) { s0[j] = f2bf(acc0[j]); s1[j] = f2bf(acc1[j]); }
    *(u16x4*)(preT + ((size_t)b * O + col0) * N + n0 + prow)      = s0;
    *(u16x4*)(preT + ((size_t)b * O + col0 + 16) * N + n0 + prow) = s1;
}

// ---------------- Kernel 2: gate (R10-form: 4 lanes/pair, 65536 blocks) -------------
__global__ __launch_bounds__(256)
void gate_kernel(const float* __restrict__ ef,
                 const float* __restrict__ we,
                 const float* __restrict__ be,
                 const float* __restrict__ sup1,
                 unsigned short* __restrict__ G) {
    const size_t tid  = (size_t)blockIdx.x * 256 + threadIdx.x;
    const size_t pair = tid >> 2;
    const int    sub  = (int)(threadIdx.x & 3);
    const float4 e4 = ((const float4*)ef)[pair * 4 + sub];
    const float4 w4 = ((const float4*)we)[pair * 4 + sub];
    float v = e4.x * w4.x + e4.y * w4.y + e4.z * w4.z + e4.w * w4.w;
    v += __shfl_xor(v, 1);
    v += __shfl_xor(v, 2);
    if (sub == 0) {
        const float t = v + be[pair];
        const float g = (1.f / (1.f + __expf(-t))) * sup1[pair];
        G[pair] = f2bf(g);
    }
}

// ---------------- Kernel 3: dual GEMM, 8-wave in-block split-K (R10 form) -----------
__global__ __launch_bounds__(512, 4)
void gemm_direct(const float* __restrict__ S0,
                 const unsigned short* __restrict__ G,
                 const unsigned short* __restrict__ preT,
                 const float* __restrict__ bias,
                 float* __restrict__ out) {
    __shared__ float red[8][16][36];

    const int bx   = blockIdx.x;
    const int orig = (bx & 7) * 64 + (bx >> 3);  // group 4 col-blocks per XCD
    const int rb   = orig >> 2;                  // 0..127
    const int cg   = orig & 3;                   // 0..3
    const int n0   = rb * 16;

    const int t    = threadIdx.x;
    const int lane = t & 63;
    const int wv   = t >> 6;                     // 0..7
    const int m_b  = wv * 256;
    const int row  = lane & 15;
    const int kg   = lane >> 4;
    const int col0 = cg * 32 + row;

    const float*          aS = S0   + (size_t)(n0 + row) * N + m_b + kg * 8;
    const unsigned short* aG = G    + (size_t)(n0 + row) * N + m_b + kg * 8;
    const unsigned short* b0 = preT + (size_t)col0 * N        + m_b + kg * 8;
    const unsigned short* b1 = b0 + (size_t)16 * N;
    const unsigned short* c0 = b0 + (size_t)O * N;   // preT[1]
    const unsigned short* c1 = b1 + (size_t)O * N;

    floatx4 acc0 = {0.f, 0.f, 0.f, 0.f};
    floatx4 acc1 = {0.f, 0.f, 0.f, 0.f};

#pragma unroll 2
    for (int s = 0; s < 8; ++s) {
        const int mo = s * 32;
        const float4 f0 = *(const float4*)(aS + mo);
        const float4 f1 = *(const float4*)(aS + mo + 4);
        const shortx8 a_g = *(const shortx8*)(aG + mo);
        const shortx8 b00 = *(const shortx8*)(b0 + mo);
        const shortx8 b01 = *(const shortx8*)(b1 + mo);
        const shortx8 b10 = *(const shortx8*)(c0 + mo);
        const shortx8 b11 = *(const shortx8*)(c1 + mo);
        shortx8 a_s;
        a_s[0] = (short)f2bf(f0.x); a_s[1] = (short)f2bf(f0.y);
        a_s[2] = (short)f2bf(f0.z); a_s[3] = (short)f2bf(f0.w);
        a_s[4] = (short)f2bf(f1.x); a_s[5] = (short)f2bf(f1.y);
        a_s[6] = (short)f2bf(f1.z); a_s[7] = (short)f2bf(f1.w);
        acc0 = __builtin_amdgcn_mfma_f32_16x16x32_bf16(a_s, b00, acc0, 0, 0, 0);
        acc0 = __builtin_amdgcn_mfma_f32_16x16x32_bf16(a_g, b10, acc0, 0, 0, 0);
        acc1 = __builtin_amdgcn_mfma_f32_16x16x32_bf16(a_s, b01, acc1, 0, 0, 0);
        acc1 = __builtin_amdgcn_mfma_f32_16x16x32_bf16(a_g, b11, acc1, 0, 0, 0);
    }

    // stash per-wave acc in LDS: C/D col = lane&15, row = kg*4 + j
    const int prow = kg * 4;
#pragma unroll
    for (int j = 0; j < 4; ++j) {
        red[wv][prow + j][row]      = acc0[j];
        red[wv][prow + j][16 + row] = acc1[j];
    }
    __syncthreads();

    // first 256 threads: one row r, two cols c,c+1; sum over 8 waves
    if (t < 256) {
        const int r = t >> 4;
        const int c = (t & 15) * 2;
        float v0 = 0.f, v1 = 0.f;
#pragma unroll
        for (int w = 0; w < 8; ++w) {
            v0 += red[w][r][c];
            v1 += red[w][r][c + 1];
        }
        v0 = fmaxf(v0 + bias[cg * 32 + c],     0.f);
        v1 = fmaxf(v1 + bias[cg * 32 + c + 1], 0.f);
        float2 o2; o2.x = v0; o2.y = v1;
        *(float2*)(out + (size_t)(n0 + r) * O + cg * 32 + c) = o2;
    }
}

extern "C" void kernel_launch(void* const* d_in, const int* in_sizes, int n_in,
                              void* d_out, int out_size, void* d_ws, size_t ws_size,
                              hipStream_t stream) {
    const float* x   = (const float*)d_in[0];   // [N,F]
    const float* sup = (const float*)d_in[1];   // [2,N,N]
    const float* ef  = (const float*)d_in[2];   // [N,N,E]
    const float* we  = (const float*)d_in[3];   // [N,N,E]
    const float* be  = (const float*)d_in[4];   // [N,N]
    const float* w0  = (const float*)d_in[5];   // [F,O]
    const float* w1  = (const float*)d_in[6];   // [F,O]
    const float* b   = (const float*)d_in[7];   // [O]
    float* out = (float*)d_out;

    unsigned short* preT = (unsigned short*)d_ws;    // [2][O][N] bf16, 1 MB
    unsigned short* G    = preT + 2 * (size_t)N * O; // [N][N]   bf16, 8.4 MB

    pre_t<<<dim3(N / 16, 2), 256, 0, stream>>>(x, w0, w1, preT);
    gate_kernel<<<(unsigned)((size_t)N * N * 4 / 256), 256, 0, stream>>>(
        ef, we, be, sup + (size_t)N * N, G);
    gemm_direct<<<512, 512, 0, stream>>>(sup, G, preT, b, out);
}